// Round 1
// baseline (2729.165 us; speedup 1.0000x reference)
//
#include <hip/hip_runtime.h>

// PhysNetCore: N=100k atoms, F=64, R=16, P=1.6M pairs, f32 in/out.
// R1 design notes:
//  - Y = sp(pe @ Wj.T + bj) computed per-ATOM then gathered (commutes with gather)
//    -> pair-side matmul eliminated (13 GFLOP -> 0.8 GFLOP).
//  - atom-side matvecs: wave processes 4 atoms; W staged in LDS transposed [k][f]
//    (lane=f -> conflict-free b32), activation rows broadcast via float4 LDS reads.
//  - scatter: 64-lane f32 atomicAdd per pair (device-scope, XCD-safe).

#define NATOMS 100000
#define F 64
#define RDIM 16
#define NPAIRS 1600000
#define AOUT 2

__device__ __forceinline__ float sp(float x) {
    // softplus = max(x,0) + log1p(exp(-|x|)); fast intrinsics, abs err ~1e-6
    return fmaxf(x, 0.f) + __logf(1.f + __expf(-fabsf(x)));
}

// out[q] = sum_k rows[q][k] * W[k*64+lane]   (W transposed in LDS: [k][f])
__device__ __forceinline__ void mv64x4(const float* __restrict__ W,
                                       const float* __restrict__ rows,
                                       int lane, float out[4]) {
    float a0[4], a1[4], a2[4], a3[4];
#pragma unroll
    for (int q = 0; q < 4; ++q) { a0[q] = a1[q] = a2[q] = a3[q] = 0.f; }
#pragma unroll
    for (int k4 = 0; k4 < 16; ++k4) {
        const int k = k4 * 4;
        const float w0 = W[(k + 0) * F + lane];
        const float w1 = W[(k + 1) * F + lane];
        const float w2 = W[(k + 2) * F + lane];
        const float w3 = W[(k + 3) * F + lane];
#pragma unroll
        for (int q = 0; q < 4; ++q) {
            const float4 h = *(const float4*)(rows + q * F + k);  // broadcast read
            a0[q] = fmaf(h.x, w0, a0[q]);
            a1[q] = fmaf(h.y, w1, a1[q]);
            a2[q] = fmaf(h.z, w2, a2[q]);
            a3[q] = fmaf(h.w, w3, a3[q]);
        }
    }
#pragma unroll
    for (int q = 0; q < 4; ++q) out[q] = (a0[q] + a1[q]) + (a2[q] + a3[q]);
}

// K1: pe = sp(emb); v0 = sp(pe@Wi.T+bi); Y = sp(pe@Wj.T+bj)
__global__ __launch_bounds__(1024) void k_init(
    const float* __restrict__ emb,
    const float* __restrict__ Wi, const float* __restrict__ bi,
    const float* __restrict__ Wj, const float* __restrict__ bj,
    float* __restrict__ v, float* __restrict__ Y)
{
    __shared__ float sWi[F * F];
    __shared__ float sWj[F * F];
    __shared__ float srow[16][4 * F];
    const int tid = threadIdx.x;
    for (int idx = tid; idx < F * F; idx += 1024) {
        const int f = idx & 63, k = idx >> 6;   // sW[k][f] = W[f][k]
        sWi[idx] = Wi[f * F + k];
        sWj[idx] = Wj[f * F + k];
    }
    __syncthreads();
    const int wv = tid >> 6, lane = tid & 63;
    const float bi_l = bi[lane], bj_l = bj[lane];
    for (int base = blockIdx.x * 64; base < NATOMS; base += gridDim.x * 64) {
        const int a0 = base + wv * 4;
#pragma unroll
        for (int q = 0; q < 4; ++q) {
            const int a = a0 + q;
            srow[wv][q * F + lane] = (a < NATOMS) ? sp(emb[a * F + lane]) : 0.f;
        }
        __syncthreads();
        float oi[4], oj[4];
        mv64x4(sWi, srow[wv], lane, oi);
        mv64x4(sWj, srow[wv], lane, oj);
#pragma unroll
        for (int q = 0; q < 4; ++q) {
            const int a = a0 + q;
            if (a < NATOMS) {
                v[a * F + lane] = sp(oi[q] + bi_l);
                Y[a * F + lane] = sp(oj[q] + bj_l);
            }
        }
        __syncthreads();
    }
}

// K2: per pair p: g = f_ij[p] @ Wg.T ; atomicAdd(v[idx_i], Y[idx_j] * g)
__global__ __launch_bounds__(256) void k_pairs(
    const float* __restrict__ fij, const int* __restrict__ pidx,
    const float* __restrict__ Wg, const float* __restrict__ Y,
    float* __restrict__ v)
{
    const int lane = threadIdx.x & 63;
    const int wid = blockIdx.x * 4 + (threadIdx.x >> 6);
    const int nw = gridDim.x * 4;
    float wg[16];
    {
        const float4* s = (const float4*)(Wg + lane * RDIM);  // lane f holds Wg[f][0..15]
        const float4 x0 = s[0], x1 = s[1], x2 = s[2], x3 = s[3];
        wg[0] = x0.x; wg[1] = x0.y; wg[2]  = x0.z; wg[3]  = x0.w;
        wg[4] = x1.x; wg[5] = x1.y; wg[6]  = x1.z; wg[7]  = x1.w;
        wg[8] = x2.x; wg[9] = x2.y; wg[10] = x2.z; wg[11] = x2.w;
        wg[12] = x3.x; wg[13] = x3.y; wg[14] = x3.z; wg[15] = x3.w;
    }
    for (int p0 = wid * 4; p0 < NPAIRS; p0 += nw * 4) {
        const float fv = fij[p0 * RDIM + lane];  // 4 pairs' radials, coalesced 256B
#pragma unroll
        for (int qq = 0; qq < 4; ++qq) {
            const int p = p0 + qq;
            const int ii = pidx[p];
            const int jj = pidx[NPAIRS + p];
            float g = 0.f;
#pragma unroll
            for (int r = 0; r < RDIM; ++r)   // broadcast via readlane (wave-uniform idx)
                g = fmaf(__shfl(fv, qq * 16 + r, 64), wg[r], g);
            const float yv = Y[jj * F + lane];
            atomicAdd(v + ii * F + lane, yv * g);
        }
    }
}

// K3a: 3 interaction residuals on v, then u = gate*pe + sp(v)@Wv.T + bv
__global__ __launch_bounds__(1024) void k_res_in(
    const float* __restrict__ emb,
    const float* __restrict__ rW1, const float* __restrict__ rb1,
    const float* __restrict__ rW2, const float* __restrict__ rb2,
    const float* __restrict__ Wv, const float* __restrict__ bv,
    const float* __restrict__ gate, const float* __restrict__ vin,
    float* __restrict__ uout)
{
    extern __shared__ float sm[];
    float* sW = sm;                 // 7 matrices [k][f]
    float* srow = sm + 7 * F * F;   // [16 waves][4*64]
    const int tid = threadIdx.x;
    for (int idx = tid; idx < 7 * F * F; idx += 1024) {
        const int m = idx >> 12, qq = idx & 4095;
        const int f = qq & 63, k = qq >> 6;
        const float* src = (m < 3) ? (rW1 + m * F * F)
                                   : (m < 6 ? (rW2 + (m - 3) * F * F) : Wv);
        sW[idx] = src[f * F + k];
    }
    __syncthreads();
    const int wv = tid >> 6, lane = tid & 63;
    float* myrow = srow + wv * (4 * F);
    const float gl = gate[lane], bvl = bv[lane];
    for (int base = blockIdx.x * 64; base < NATOMS; base += gridDim.x * 64) {
        const int a0 = base + wv * 4;
        float vv[4];
#pragma unroll
        for (int q = 0; q < 4; ++q) {
            const int a = a0 + q;
            vv[q] = (a < NATOMS) ? vin[a * F + lane] : 0.f;
        }
#pragma unroll
        for (int r = 0; r < 3; ++r) {
            __syncthreads();
#pragma unroll
            for (int q = 0; q < 4; ++q) myrow[q * F + lane] = sp(vv[q]);
            __syncthreads();
            float t[4];
            mv64x4(sW + r * F * F, myrow, lane, t);
            const float b1l = rb1[r * F + lane];
            __syncthreads();
#pragma unroll
            for (int q = 0; q < 4; ++q) myrow[q * F + lane] = sp(t[q] + b1l);
            __syncthreads();
            float o[4];
            mv64x4(sW + (3 + r) * F * F, myrow, lane, o);
            const float b2l = rb2[r * F + lane];
#pragma unroll
            for (int q = 0; q < 4; ++q) vv[q] += o[q] + b2l;
        }
        __syncthreads();
#pragma unroll
        for (int q = 0; q < 4; ++q) myrow[q * F + lane] = sp(vv[q]);
        __syncthreads();
        float u[4];
        mv64x4(sW + 6 * F * F, myrow, lane, u);
#pragma unroll
        for (int q = 0; q < 4; ++q) {
            const int a = a0 + q;
            if (a < NATOMS) {
                const float pe = sp(emb[a * F + lane]);
                uout[a * F + lane] = gl * pe + u[q] + bvl;
            }
        }
        __syncthreads();
    }
}

// K3b: 2 output residuals on x=u, then pred = x @ Wout.T + bout  (A=2)
__global__ __launch_bounds__(1024) void k_res_out(
    const float* __restrict__ uin,
    const float* __restrict__ rW1, const float* __restrict__ rb1,
    const float* __restrict__ rW2, const float* __restrict__ rb2,
    const float* __restrict__ Wout, const float* __restrict__ bout,
    float* __restrict__ pred)
{
    extern __shared__ float sm[];
    float* sW = sm;                 // 4 matrices [k][f]
    float* srow = sm + 4 * F * F;
    const int tid = threadIdx.x;
    for (int idx = tid; idx < 4 * F * F; idx += 1024) {
        const int m = idx >> 12, qq = idx & 4095;
        const int f = qq & 63, k = qq >> 6;
        const float* src = (m < 2) ? (rW1 + m * F * F) : (rW2 + (m - 2) * F * F);
        sW[idx] = src[f * F + k];
    }
    __syncthreads();
    const int wv = tid >> 6, lane = tid & 63;
    float* myrow = srow + wv * (4 * F);
    const float w0 = Wout[lane], w1 = Wout[F + lane];
    const float b0 = bout[0], b1 = bout[1];
    for (int base = blockIdx.x * 64; base < NATOMS; base += gridDim.x * 64) {
        const int a0 = base + wv * 4;
        float x[4];
#pragma unroll
        for (int q = 0; q < 4; ++q) {
            const int a = a0 + q;
            x[q] = (a < NATOMS) ? uin[a * F + lane] : 0.f;
        }
#pragma unroll
        for (int r = 0; r < 2; ++r) {
            __syncthreads();
#pragma unroll
            for (int q = 0; q < 4; ++q) myrow[q * F + lane] = sp(x[q]);
            __syncthreads();
            float t[4];
            mv64x4(sW + r * F * F, myrow, lane, t);
            const float b1l = rb1[r * F + lane];
            __syncthreads();
#pragma unroll
            for (int q = 0; q < 4; ++q) myrow[q * F + lane] = sp(t[q] + b1l);
            __syncthreads();
            float o[4];
            mv64x4(sW + (2 + r) * F * F, myrow, lane, o);
            const float b2l = rb2[r * F + lane];
#pragma unroll
            for (int q = 0; q < 4; ++q) x[q] += o[q] + b2l;
        }
#pragma unroll
        for (int q = 0; q < 4; ++q) {
            float s0 = x[q] * w0, s1 = x[q] * w1;
#pragma unroll
            for (int off = 32; off; off >>= 1) {
                s0 += __shfl_xor(s0, off, 64);
                s1 += __shfl_xor(s1, off, 64);
            }
            const int a = a0 + q;
            if (a < NATOMS && lane == 0) {
                pred[a * AOUT + 0] = s0 + b0;
                pred[a * AOUT + 1] = s1 + b1;
            }
        }
        __syncthreads();
    }
}

extern "C" void kernel_launch(void* const* d_in, const int* in_sizes, int n_in,
                              void* d_out, int out_size, void* d_ws, size_t ws_size,
                              hipStream_t stream)
{
    const float* emb    = (const float*)d_in[0];
    const float* fij    = (const float*)d_in[1];
    const int*   pidx   = (const int*)d_in[2];
    const float* Wg     = (const float*)d_in[3];
    const float* Wi     = (const float*)d_in[4];
    const float* bi     = (const float*)d_in[5];
    const float* Wj     = (const float*)d_in[6];
    const float* bj     = (const float*)d_in[7];
    const float* Wv     = (const float*)d_in[8];
    const float* bv     = (const float*)d_in[9];
    const float* gate   = (const float*)d_in[10];
    const float* rinW1  = (const float*)d_in[11];
    const float* rinb1  = (const float*)d_in[12];
    const float* rinW2  = (const float*)d_in[13];
    const float* rinb2  = (const float*)d_in[14];
    const float* routW1 = (const float*)d_in[15];
    const float* routb1 = (const float*)d_in[16];
    const float* routW2 = (const float*)d_in[17];
    const float* routb2 = (const float*)d_in[18];
    const float* Wout   = (const float*)d_in[19];
    const float* bout   = (const float*)d_in[20];

    float* pred = (float*)d_out;                    // [N,2]
    float* uemb = (float*)d_out + NATOMS * AOUT;    // [N,64]

    float* v = (float*)d_ws;                        // [N,64]
    float* Y = v + NATOMS * F;                      // [N,64]

    const size_t lds3a = (size_t)(7 * F * F + 16 * 4 * F) * sizeof(float);  // 128 KiB
    const size_t lds3b = (size_t)(4 * F * F + 16 * 4 * F) * sizeof(float);  // 80 KiB
    (void)hipFuncSetAttribute((const void*)k_res_in,
                              hipFuncAttributeMaxDynamicSharedMemorySize, (int)lds3a);
    (void)hipFuncSetAttribute((const void*)k_res_out,
                              hipFuncAttributeMaxDynamicSharedMemorySize, (int)lds3b);

    k_init<<<512, 1024, 0, stream>>>(emb, Wi, bi, Wj, bj, v, Y);
    k_pairs<<<2048, 256, 0, stream>>>(fij, pidx, Wg, Y, v);
    k_res_in<<<256, 1024, lds3a, stream>>>(emb, rinW1, rinb1, rinW2, rinb2,
                                           Wv, bv, gate, v, uemb);
    k_res_out<<<512, 1024, lds3b, stream>>>(uemb, routW1, routb1, routW2, routb2,
                                            Wout, bout, pred);
}

// Round 2
// 1048.691 us; speedup vs baseline: 2.6024x; 2.6024x over previous
//
#include <hip/hip_runtime.h>

// PhysNetCore: N=100k atoms, F=64, R=16, P=1.6M pairs, f32 in/out.
// R2 design:
//  - Dense matvecs: activations stay in REGISTERS (lane = feature); the k-broadcast
//    uses v_readlane (VALU) instead of LDS-broadcast ds_read_b128 -> LDS pipe freed,
//    work spreads over 4 SIMDs. Weights packed in LDS as [k4][f][4] so one
//    conflict-free ds_read_b128 per wave serves 4 k-steps for 8 atoms.
//  - No __syncthreads in any inner loop (only after weight staging).
//  - k_pairs: readlane (not __shfl/ds_bpermute) for the radial broadcast; Y-gather
//    loads issued before gate math; 64-lane f32 atomicAdd scatter kept.

#define NATOMS 100000
#define F 64
#define RDIM 16
#define NPAIRS 1600000
#define AOUT 2

__device__ __forceinline__ float sp(float x) {
    // softplus = max(x,0) + log1p(exp(-|x|))
    return fmaxf(x, 0.f) + __logf(1.f + __expf(-fabsf(x)));
}

__device__ __forceinline__ float bcast(float x, int k) {
    // broadcast lane k's value to all lanes via SGPR (VALU pipe, not LDS)
    return __uint_as_float(__builtin_amdgcn_readlane(__float_as_uint(x), k));
}

// stage row-major W[64][64] into packed [k4][f][4]: dst[k4*256 + f*4 + kk] = W[f][k4*4+kk]
__device__ __forceinline__ void stageW(float* dst, const float* __restrict__ src,
                                       int tid, int nth) {
    for (int idx = tid; idx < 1024; idx += nth) {
        const int k4 = idx >> 6, f = idx & 63;
        const float4 w = *(const float4*)(src + f * F + k4 * 4);
        *(float4*)(dst + k4 * 256 + f * 4) = w;
    }
}

// acc[a](lane=f) = sum_k h[a][k] * W[f][k]; h distributed lane=feature.
template <int NB>
__device__ __forceinline__ void mv_rl(const float* __restrict__ sW,
                                      const float h[NB], float acc[NB], int lane) {
#pragma unroll
    for (int a = 0; a < NB; ++a) acc[a] = 0.f;
    const float* wp = sW + lane * 4;
#pragma unroll 4
    for (int k4 = 0; k4 < 16; ++k4) {
        const float4 w = *(const float4*)(wp + k4 * 256);  // conflict-free b128
#pragma unroll
        for (int kk = 0; kk < 4; ++kk) {
            const float wk = (kk == 0) ? w.x : (kk == 1) ? w.y : (kk == 2) ? w.z : w.w;
            const int k = k4 * 4 + kk;
#pragma unroll
            for (int a = 0; a < NB; ++a)
                acc[a] = fmaf(bcast(h[a], k), wk, acc[a]);
        }
    }
}

// K1: pe = sp(emb); v0 = sp(pe@Wi.T+bi); Y = sp(pe@Wj.T+bj)
__global__ __launch_bounds__(256) void k_init(
    const float* __restrict__ emb,
    const float* __restrict__ Wi, const float* __restrict__ bi,
    const float* __restrict__ Wj, const float* __restrict__ bj,
    float* __restrict__ v, float* __restrict__ Y)
{
    __shared__ float sWi[1024 * 4];
    __shared__ float sWj[1024 * 4];
    stageW(sWi, Wi, threadIdx.x, 256);
    stageW(sWj, Wj, threadIdx.x, 256);
    __syncthreads();
    const int lane = threadIdx.x & 63;
    const int gw = blockIdx.x * 4 + (threadIdx.x >> 6);
    const int gws = gridDim.x * 4;
    const float bil = bi[lane], bjl = bj[lane];
    for (int a0 = gw * 8; a0 < NATOMS; a0 += gws * 8) {   // NATOMS % 8 == 0
        float h[8], oi[8], oj[8];
#pragma unroll
        for (int a = 0; a < 8; ++a) h[a] = sp(emb[(a0 + a) * F + lane]);
        mv_rl<8>(sWi, h, oi, lane);
        mv_rl<8>(sWj, h, oj, lane);
#pragma unroll
        for (int a = 0; a < 8; ++a) {
            v[(a0 + a) * F + lane] = sp(oi[a] + bil);
            Y[(a0 + a) * F + lane] = sp(oj[a] + bjl);
        }
    }
}

// K2: per pair p: g[f] = f_ij[p]@Wg[f,:] ; atomicAdd(v[idx_i], Y[idx_j]*g)
__global__ __launch_bounds__(256) void k_pairs(
    const float* __restrict__ fij, const int* __restrict__ pidx,
    const float* __restrict__ Wg, const float* __restrict__ Y,
    float* __restrict__ v)
{
    const int lane = threadIdx.x & 63;
    const int wid = blockIdx.x * 4 + (threadIdx.x >> 6);
    const int nw = gridDim.x * 4;
    float wg[16];
    {
        const float4* s = (const float4*)(Wg + lane * RDIM);  // lane f: Wg[f][0..15]
        const float4 x0 = s[0], x1 = s[1], x2 = s[2], x3 = s[3];
        wg[0] = x0.x; wg[1] = x0.y; wg[2]  = x0.z; wg[3]  = x0.w;
        wg[4] = x1.x; wg[5] = x1.y; wg[6]  = x1.z; wg[7]  = x1.w;
        wg[8] = x2.x; wg[9] = x2.y; wg[10] = x2.z; wg[11] = x2.w;
        wg[12] = x3.x; wg[13] = x3.y; wg[14] = x3.z; wg[15] = x3.w;
    }
    for (int p0 = wid * 4; p0 < NPAIRS; p0 += nw * 4) {
        const float fv = fij[p0 * RDIM + lane];  // 4 pairs' radials, 256B coalesced
        int ii[4], jj[4];
        float yv[4];
#pragma unroll
        for (int q = 0; q < 4; ++q) {            // uniform -> scalar loads
            ii[q] = pidx[p0 + q];
            jj[q] = pidx[NPAIRS + p0 + q];
        }
#pragma unroll
        for (int q = 0; q < 4; ++q) yv[q] = Y[jj[q] * F + lane];  // overlap gathers
#pragma unroll
        for (int q = 0; q < 4; ++q) {
            float g = 0.f;
#pragma unroll
            for (int r = 0; r < RDIM; ++r)       // compile-time lane -> v_readlane
                g = fmaf(bcast(fv, q * 16 + r), wg[r], g);
            atomicAdd(v + ii[q] * F + lane, yv[q] * g);
        }
    }
}

// K3a: 3 interaction residuals on v, then u = gate*pe + sp(v)@Wv.T + bv
__global__ __launch_bounds__(1024) void k_res_in(
    const float* __restrict__ emb,
    const float* __restrict__ rW1, const float* __restrict__ rb1,
    const float* __restrict__ rW2, const float* __restrict__ rb2,
    const float* __restrict__ Wv, const float* __restrict__ bv,
    const float* __restrict__ gate, const float* __restrict__ vin,
    float* __restrict__ uout)
{
    extern __shared__ float sm[];  // 7 packed matrices: [0..2]=rW1, [3..5]=rW2, [6]=Wv
    for (int r = 0; r < 3; ++r) {
        stageW(sm + r * 4096, rW1 + r * F * F, threadIdx.x, 1024);
        stageW(sm + (3 + r) * 4096, rW2 + r * F * F, threadIdx.x, 1024);
    }
    stageW(sm + 6 * 4096, Wv, threadIdx.x, 1024);
    __syncthreads();
    const int lane = threadIdx.x & 63;
    const int gw = blockIdx.x * 16 + (threadIdx.x >> 6);
    const int gws = gridDim.x * 16;
    const float gl = gate[lane], bvl = bv[lane];
    for (int a0 = gw * 8; a0 < NATOMS; a0 += gws * 8) {
        float vv[8], h[8], t[8];
#pragma unroll
        for (int a = 0; a < 8; ++a) vv[a] = vin[(a0 + a) * F + lane];
#pragma unroll 1
        for (int r = 0; r < 3; ++r) {
            const float b1l = rb1[r * F + lane], b2l = rb2[r * F + lane];
#pragma unroll
            for (int a = 0; a < 8; ++a) h[a] = sp(vv[a]);
            mv_rl<8>(sm + r * 4096, h, t, lane);
#pragma unroll
            for (int a = 0; a < 8; ++a) h[a] = sp(t[a] + b1l);
            mv_rl<8>(sm + (3 + r) * 4096, h, t, lane);
#pragma unroll
            for (int a = 0; a < 8; ++a) vv[a] += t[a] + b2l;
        }
#pragma unroll
        for (int a = 0; a < 8; ++a) h[a] = sp(vv[a]);
        mv_rl<8>(sm + 6 * 4096, h, t, lane);
#pragma unroll
        for (int a = 0; a < 8; ++a) {
            const float pe = sp(emb[(a0 + a) * F + lane]);
            uout[(a0 + a) * F + lane] = gl * pe + t[a] + bvl;
        }
    }
}

// K3b: 2 output residuals on x=u, then pred = x @ Wout.T + bout  (A=2)
__global__ __launch_bounds__(1024) void k_res_out(
    const float* __restrict__ uin,
    const float* __restrict__ rW1, const float* __restrict__ rb1,
    const float* __restrict__ rW2, const float* __restrict__ rb2,
    const float* __restrict__ Wout, const float* __restrict__ bout,
    float* __restrict__ pred)
{
    extern __shared__ float sm[];  // 4 packed matrices: [0..1]=rW1, [2..3]=rW2
    for (int r = 0; r < 2; ++r) {
        stageW(sm + r * 4096, rW1 + r * F * F, threadIdx.x, 1024);
        stageW(sm + (2 + r) * 4096, rW2 + r * F * F, threadIdx.x, 1024);
    }
    __syncthreads();
    const int lane = threadIdx.x & 63;
    const int gw = blockIdx.x * 16 + (threadIdx.x >> 6);
    const int gws = gridDim.x * 16;
    const float w0l = Wout[lane], w1l = Wout[F + lane];
    const float b0 = bout[0], b1 = bout[1];
    for (int a0 = gw * 8; a0 < NATOMS; a0 += gws * 8) {
        float x[8], h[8], t[8];
#pragma unroll
        for (int a = 0; a < 8; ++a) x[a] = uin[(a0 + a) * F + lane];
#pragma unroll 1
        for (int r = 0; r < 2; ++r) {
            const float b1l = rb1[r * F + lane], b2l = rb2[r * F + lane];
#pragma unroll
            for (int a = 0; a < 8; ++a) h[a] = sp(x[a]);
            mv_rl<8>(sm + r * 4096, h, t, lane);
#pragma unroll
            for (int a = 0; a < 8; ++a) h[a] = sp(t[a] + b1l);
            mv_rl<8>(sm + (2 + r) * 4096, h, t, lane);
#pragma unroll
            for (int a = 0; a < 8; ++a) x[a] += t[a] + b2l;
        }
#pragma unroll
        for (int a = 0; a < 8; ++a) {
            float s0 = x[a] * w0l, s1 = x[a] * w1l;
#pragma unroll
            for (int off = 32; off; off >>= 1) {
                s0 += __shfl_xor(s0, off, 64);
                s1 += __shfl_xor(s1, off, 64);
            }
            if (lane == 0) {
                pred[(a0 + a) * AOUT + 0] = s0 + b0;
                pred[(a0 + a) * AOUT + 1] = s1 + b1;
            }
        }
    }
}

extern "C" void kernel_launch(void* const* d_in, const int* in_sizes, int n_in,
                              void* d_out, int out_size, void* d_ws, size_t ws_size,
                              hipStream_t stream)
{
    const float* emb    = (const float*)d_in[0];
    const float* fij    = (const float*)d_in[1];
    const int*   pidx   = (const int*)d_in[2];
    const float* Wg     = (const float*)d_in[3];
    const float* Wi     = (const float*)d_in[4];
    const float* bi     = (const float*)d_in[5];
    const float* Wj     = (const float*)d_in[6];
    const float* bj     = (const float*)d_in[7];
    const float* Wv     = (const float*)d_in[8];
    const float* bv     = (const float*)d_in[9];
    const float* gate   = (const float*)d_in[10];
    const float* rinW1  = (const float*)d_in[11];
    const float* rinb1  = (const float*)d_in[12];
    const float* rinW2  = (const float*)d_in[13];
    const float* rinb2  = (const float*)d_in[14];
    const float* routW1 = (const float*)d_in[15];
    const float* routb1 = (const float*)d_in[16];
    const float* routW2 = (const float*)d_in[17];
    const float* routb2 = (const float*)d_in[18];
    const float* Wout   = (const float*)d_in[19];
    const float* bout   = (const float*)d_in[20];

    float* pred = (float*)d_out;                    // [N,2]
    float* uemb = (float*)d_out + NATOMS * AOUT;    // [N,64]

    float* v = (float*)d_ws;                        // [N,64]
    float* Y = v + NATOMS * F;                      // [N,64]

    const size_t lds3a = (size_t)(7 * 4096) * sizeof(float);  // 112 KiB
    const size_t lds3b = (size_t)(4 * 4096) * sizeof(float);  // 64 KiB
    (void)hipFuncSetAttribute((const void*)k_res_in,
                              hipFuncAttributeMaxDynamicSharedMemorySize, (int)lds3a);
    (void)hipFuncSetAttribute((const void*)k_res_out,
                              hipFuncAttributeMaxDynamicSharedMemorySize, (int)lds3b);

    k_init<<<2048, 256, 0, stream>>>(emb, Wi, bi, Wj, bj, v, Y);
    k_pairs<<<2048, 256, 0, stream>>>(fij, pidx, Wg, Y, v);
    k_res_in<<<256, 1024, lds3a, stream>>>(emb, rinW1, rinb1, rinW2, rinb2,
                                           Wv, bv, gate, v, uemb);
    k_res_out<<<512, 1024, lds3b, stream>>>(uemb, routW1, routb1, routW2, routb2,
                                            Wout, bout, pred);
}

// Round 4
// 921.466 us; speedup vs baseline: 2.9618x; 1.1381x over previous
//
#include <hip/hip_runtime.h>

// PhysNetCore: N=100k atoms, F=64, R=16, P=1.6M pairs, f32 in/out.
// R4 design:
//  - Dense matvecs: lane = ATOM. Activations in LDS rows [atom][68-pad dwords]
//    (b128-aligned, standard conflict-free pattern). Weights pre-transposed to
//    ws (Wt[k][f] contiguous) -> wave-uniform rows feed s_load; inner loop is
//    v_fmac acc[f], s_w[f], v_hk : 64 FMA/atom/matvec = f32 optimum.
//  - k_res fuses interaction residuals + Wv + output residuals + Wout;
//    chain stays in registers; one LDS round-trip per matvec input.
//  - v aliased onto d_out's uemb region (row-disjoint per group, race-free):
//    ws = Y (25.6MB) + Wt (212KB) only.
//  - k_pairs: exact R2 version (atomicAdd f32; pk atomic doesn't exist on gfx950).

#define NATOMS 100000
#define F 64
#define RDIM 16
#define NPAIRS 1600000
#define AOUT 2
#define NGROUPS 1563          // ceil(NATOMS/64)
#define HPAD 68               // LDS row stride in dwords (16B-aligned)

__device__ __forceinline__ float sp(float x) {
    // softplus = max(x,0) + log1p(exp(-|x|))
    return fmaxf(x, 0.f) + __logf(1.f + __expf(-fabsf(x)));
}

__device__ __forceinline__ float bcast(float x, int k) {
    return __uint_as_float(__builtin_amdgcn_readlane(__float_as_uint(x), k));
}

// acc[f] = bias[f] + sum_k hp[k] * wt[k*64+f]; hp = lane's LDS activation row.
__device__ __forceinline__ void mv64(const float* __restrict__ hp,
                                     const float* __restrict__ wt,
                                     const float* __restrict__ bias,
                                     float acc[64]) {
#pragma unroll
    for (int f4 = 0; f4 < 16; ++f4) {
        const float4 b = *(const float4*)(bias + f4 * 4);   // uniform -> s_load
        acc[4*f4+0] = b.x; acc[4*f4+1] = b.y; acc[4*f4+2] = b.z; acc[4*f4+3] = b.w;
    }
#pragma unroll 1
    for (int k4 = 0; k4 < 16; ++k4) {
        const float4 h4 = *(const float4*)(hp + k4 * 4);    // ds_read_b128
        const float* w = wt + k4 * 4 * F;                   // 4 W.T rows (uniform)
#pragma unroll
        for (int f4 = 0; f4 < 16; ++f4) {
            const float4 w0 = *(const float4*)(w + f4 * 4);
            acc[4*f4+0] = fmaf(w0.x, h4.x, acc[4*f4+0]);
            acc[4*f4+1] = fmaf(w0.y, h4.x, acc[4*f4+1]);
            acc[4*f4+2] = fmaf(w0.z, h4.x, acc[4*f4+2]);
            acc[4*f4+3] = fmaf(w0.w, h4.x, acc[4*f4+3]);
        }
#pragma unroll
        for (int f4 = 0; f4 < 16; ++f4) {
            const float4 w1 = *(const float4*)(w + F + f4 * 4);
            acc[4*f4+0] = fmaf(w1.x, h4.y, acc[4*f4+0]);
            acc[4*f4+1] = fmaf(w1.y, h4.y, acc[4*f4+1]);
            acc[4*f4+2] = fmaf(w1.z, h4.y, acc[4*f4+2]);
            acc[4*f4+3] = fmaf(w1.w, h4.y, acc[4*f4+3]);
        }
#pragma unroll
        for (int f4 = 0; f4 < 16; ++f4) {
            const float4 w2 = *(const float4*)(w + 2 * F + f4 * 4);
            acc[4*f4+0] = fmaf(w2.x, h4.z, acc[4*f4+0]);
            acc[4*f4+1] = fmaf(w2.y, h4.z, acc[4*f4+1]);
            acc[4*f4+2] = fmaf(w2.z, h4.z, acc[4*f4+2]);
            acc[4*f4+3] = fmaf(w2.w, h4.z, acc[4*f4+3]);
        }
#pragma unroll
        for (int f4 = 0; f4 < 16; ++f4) {
            const float4 w3 = *(const float4*)(w + 3 * F + f4 * 4);
            acc[4*f4+0] = fmaf(w3.x, h4.w, acc[4*f4+0]);
            acc[4*f4+1] = fmaf(w3.y, h4.w, acc[4*f4+1]);
            acc[4*f4+2] = fmaf(w3.z, h4.w, acc[4*f4+2]);
            acc[4*f4+3] = fmaf(w3.w, h4.w, acc[4*f4+3]);
        }
    }
}

// P0: transpose 13 64x64 weight matrices into ws: Wt[m][k*64+f] = W_m[f*64+k]
__global__ __launch_bounds__(1024) void k_prepw(
    const float* __restrict__ Wi, const float* __restrict__ Wj,
    const float* __restrict__ r1, const float* __restrict__ r2,
    const float* __restrict__ Wv, const float* __restrict__ o1,
    const float* __restrict__ o2, float* __restrict__ Wt)
{
    const int m = blockIdx.x;
    const float* src;
    if      (m == 0) src = Wi;
    else if (m == 1) src = Wj;
    else if (m <  5) src = r1 + (m - 2) * 4096;
    else if (m <  8) src = r2 + (m - 5) * 4096;
    else if (m == 8) src = Wv;
    else if (m < 11) src = o1 + (m - 9) * 4096;
    else             src = o2 + (m - 11) * 4096;
    for (int idx = threadIdx.x; idx < 4096; idx += 1024) {
        const int k = idx >> 6, f = idx & 63;
        Wt[m * 4096 + k * 64 + f] = src[f * 64 + k];
    }
}

// K1: pe = sp(emb); v0 = sp(pe@Wi.T+bi); Y = sp(pe@Wj.T+bj)
__global__ __launch_bounds__(512) void k_init(
    const float* __restrict__ emb, const float* __restrict__ Wt,
    const float* __restrict__ bi, const float* __restrict__ bj,
    float* __restrict__ v, float* __restrict__ Y)
{
    extern __shared__ float sm[];
    const int lane = threadIdx.x & 63, wv = threadIdx.x >> 6;
    float* hl = sm + wv * (64 * HPAD);
    const int g = blockIdx.x + gridDim.x * wv;
    if (g >= NGROUPS) return;
    const int base = g * 64;
    // stage sp(emb) lane=feature (coalesced load -> LDS)
#pragma unroll 1
    for (int a = 0; a < 64; ++a) {
        const int atom = base + a;
        hl[a * HPAD + lane] = (atom < NATOMS) ? sp(emb[atom * F + lane]) : 0.f;
    }
    const float* hp = hl + lane * HPAD;
    const int atom = base + lane;
    float acc[64];
    mv64(hp, Wt + 0 * 4096, bi, acc);
    if (atom < NATOMS) {
#pragma unroll
        for (int f = 0; f < 64; ++f) v[(size_t)atom * F + f] = sp(acc[f]);
    }
    mv64(hp, Wt + 1 * 4096, bj, acc);
    if (atom < NATOMS) {
#pragma unroll
        for (int f = 0; f < 64; ++f) Y[(size_t)atom * F + f] = sp(acc[f]);
    }
}

// K2: per pair p: g[f] = f_ij[p]@Wg[f,:] ; atomicAdd(v[idx_i], Y[idx_j]*g)
__global__ __launch_bounds__(256) void k_pairs(
    const float* __restrict__ fij, const int* __restrict__ pidx,
    const float* __restrict__ Wg, const float* __restrict__ Y,
    float* __restrict__ v)
{
    const int lane = threadIdx.x & 63;
    const int wid = blockIdx.x * 4 + (threadIdx.x >> 6);
    const int nw = gridDim.x * 4;
    float wg[16];
    {
        const float4* s = (const float4*)(Wg + lane * RDIM);
        const float4 x0 = s[0], x1 = s[1], x2 = s[2], x3 = s[3];
        wg[0] = x0.x; wg[1] = x0.y; wg[2]  = x0.z; wg[3]  = x0.w;
        wg[4] = x1.x; wg[5] = x1.y; wg[6]  = x1.z; wg[7]  = x1.w;
        wg[8] = x2.x; wg[9] = x2.y; wg[10] = x2.z; wg[11] = x2.w;
        wg[12] = x3.x; wg[13] = x3.y; wg[14] = x3.z; wg[15] = x3.w;
    }
    for (int p0 = wid * 4; p0 < NPAIRS; p0 += nw * 4) {
        const float fv = fij[p0 * RDIM + lane];
        int ii[4], jj[4];
        float yv[4];
#pragma unroll
        for (int q = 0; q < 4; ++q) {
            ii[q] = pidx[p0 + q];
            jj[q] = pidx[NPAIRS + p0 + q];
        }
#pragma unroll
        for (int q = 0; q < 4; ++q) yv[q] = Y[jj[q] * F + lane];
#pragma unroll
        for (int q = 0; q < 4; ++q) {
            float g = 0.f;
#pragma unroll
            for (int r = 0; r < RDIM; ++r)
                g = fmaf(bcast(fv, q * 16 + r), wg[r], g);
            atomicAdd(v + ii[q] * F + lane, yv[q] * g);
        }
    }
}

// K3 (fused): 3 in-residuals, u = gate*pe + sp(v)@Wv.T + bv  (-> uemb),
//             2 out-residuals, pred = x@Wout.T + bout.
__global__ __launch_bounds__(512) void k_res(
    const float* __restrict__ emb, const float* __restrict__ Wt,
    const float* __restrict__ rinb1, const float* __restrict__ rinb2,
    const float* __restrict__ bv, const float* __restrict__ gate,
    const float* __restrict__ routb1, const float* __restrict__ routb2,
    const float* __restrict__ Wout, const float* __restrict__ bout,
    const float* __restrict__ vin, float* __restrict__ uemb,
    float* __restrict__ pred)
{
    extern __shared__ float sm[];
    const int lane = threadIdx.x & 63, wv = threadIdx.x >> 6;
    float* hl = sm + wv * (64 * HPAD);
    const int g = blockIdx.x + gridDim.x * wv;
    if (g >= NGROUPS) return;
    const int base = g * 64;
    const int atom = base + lane;
    float* hp_w = hl + lane * HPAD;
    const float* hp = hp_w;

    // stage vin (raw) lane=feature
#pragma unroll 1
    for (int a = 0; a < 64; ++a) {
        const int at = base + a;
        hl[a * HPAD + lane] = (at < NATOMS) ? vin[at * F + lane] : 0.f;
    }
    float vacc[64], acc[64];
#pragma unroll
    for (int f = 0; f < 64; ++f) vacc[f] = hp[f];   // lane=atom row read (b128)

    // 3 interaction residuals
#pragma unroll 1
    for (int r = 0; r < 3; ++r) {
#pragma unroll
        for (int f = 0; f < 64; ++f) hp_w[f] = sp(vacc[f]);
        mv64(hp, Wt + (2 + r) * 4096, rinb1 + r * 64, acc);
#pragma unroll
        for (int f = 0; f < 64; ++f) hp_w[f] = sp(acc[f]);
        mv64(hp, Wt + (5 + r) * 4096, rinb2 + r * 64, acc);
#pragma unroll
        for (int f = 0; f < 64; ++f) vacc[f] += acc[f];
    }
    // o = sp(v)@Wv.T + bv
#pragma unroll
    for (int f = 0; f < 64; ++f) hp_w[f] = sp(vacc[f]);
    mv64(hp, Wt + 8 * 4096, bv, acc);
    // stage pe = sp(emb) lane=feature (overwrites h; this wave's region only)
#pragma unroll 1
    for (int a = 0; a < 64; ++a) {
        const int at = base + a;
        hl[a * HPAD + lane] = (at < NATOMS) ? sp(emb[at * F + lane]) : 0.f;
    }
    // u = gate*pe + o  (gate uniform -> s_load; pe lane=atom row read)
#pragma unroll
    for (int f = 0; f < 64; ++f) vacc[f] = gate[f] * hp[f] + acc[f];
    // write u -> LDS, coalesced store of uemb
#pragma unroll
    for (int f = 0; f < 64; ++f) hp_w[f] = vacc[f];
#pragma unroll 1
    for (int a = 0; a < 64; ++a) {
        const int at = base + a;
        if (at < NATOMS) uemb[(size_t)at * F + lane] = hl[a * HPAD + lane];
    }
    // 2 output residuals
#pragma unroll 1
    for (int r = 0; r < 2; ++r) {
#pragma unroll
        for (int f = 0; f < 64; ++f) hp_w[f] = sp(vacc[f]);
        mv64(hp, Wt + (9 + r) * 4096, routb1 + r * 64, acc);
#pragma unroll
        for (int f = 0; f < 64; ++f) hp_w[f] = sp(acc[f]);
        mv64(hp, Wt + (11 + r) * 4096, routb2 + r * 64, acc);
#pragma unroll
        for (int f = 0; f < 64; ++f) vacc[f] += acc[f];
    }
    // pred = x @ Wout.T + bout  (per-lane dot over registers, 4 partials each)
    float p00 = 0.f, p01 = 0.f, p02 = 0.f, p03 = 0.f;
    float p10 = 0.f, p11 = 0.f, p12 = 0.f, p13 = 0.f;
#pragma unroll
    for (int f4 = 0; f4 < 16; ++f4) {
        const float4 w0 = *(const float4*)(Wout + f4 * 4);        // uniform
        const float4 w1 = *(const float4*)(Wout + F + f4 * 4);    // uniform
        p00 = fmaf(w0.x, vacc[4*f4+0], p00);
        p01 = fmaf(w0.y, vacc[4*f4+1], p01);
        p02 = fmaf(w0.z, vacc[4*f4+2], p02);
        p03 = fmaf(w0.w, vacc[4*f4+3], p03);
        p10 = fmaf(w1.x, vacc[4*f4+0], p10);
        p11 = fmaf(w1.y, vacc[4*f4+1], p11);
        p12 = fmaf(w1.z, vacc[4*f4+2], p12);
        p13 = fmaf(w1.w, vacc[4*f4+3], p13);
    }
    if (atom < NATOMS) {
        pred[(size_t)atom * AOUT + 0] = ((p00 + p01) + (p02 + p03)) + bout[0];
        pred[(size_t)atom * AOUT + 1] = ((p10 + p11) + (p12 + p13)) + bout[1];
    }
}

extern "C" void kernel_launch(void* const* d_in, const int* in_sizes, int n_in,
                              void* d_out, int out_size, void* d_ws, size_t ws_size,
                              hipStream_t stream)
{
    const float* emb    = (const float*)d_in[0];
    const float* fij    = (const float*)d_in[1];
    const int*   pidx   = (const int*)d_in[2];
    const float* Wg     = (const float*)d_in[3];
    const float* Wi     = (const float*)d_in[4];
    const float* bi     = (const float*)d_in[5];
    const float* Wj     = (const float*)d_in[6];
    const float* bj     = (const float*)d_in[7];
    const float* Wv     = (const float*)d_in[8];
    const float* bv     = (const float*)d_in[9];
    const float* gate   = (const float*)d_in[10];
    const float* rinW1  = (const float*)d_in[11];
    const float* rinb1  = (const float*)d_in[12];
    const float* rinW2  = (const float*)d_in[13];
    const float* rinb2  = (const float*)d_in[14];
    const float* routW1 = (const float*)d_in[15];
    const float* routb1 = (const float*)d_in[16];
    const float* routW2 = (const float*)d_in[17];
    const float* routb2 = (const float*)d_in[18];
    const float* Wout   = (const float*)d_in[19];
    const float* bout   = (const float*)d_in[20];

    float* pred = (float*)d_out;                    // [N,2]
    float* uemb = (float*)d_out + NATOMS * AOUT;    // [N,64]
    float* v    = uemb;                             // alias: v lives in uemb slot
                                                    // (row-disjoint read-then-write per group)
    float* Y  = (float*)d_ws;                       // [N,64]
    float* Wt = Y + (size_t)NATOMS * F;             // 13 * 4096 floats

    const size_t lds = (size_t)(8 * 64 * HPAD) * sizeof(float);  // 136 KiB
    (void)hipFuncSetAttribute((const void*)k_init,
                              hipFuncAttributeMaxDynamicSharedMemorySize, (int)lds);
    (void)hipFuncSetAttribute((const void*)k_res,
                              hipFuncAttributeMaxDynamicSharedMemorySize, (int)lds);

    k_prepw<<<13, 1024, 0, stream>>>(Wi, Wj, rinW1, rinW2, Wv, routW1, routW2, Wt);
    k_init<<<256, 512, lds, stream>>>(emb, Wt, bi, bj, v, Y);
    k_pairs<<<2048, 256, 0, stream>>>(fij, pidx, Wg, Y, v);
    k_res<<<256, 512, lds, stream>>>(emb, Wt, rinb1, rinb2, bv, gate,
                                     routb1, routb2, Wout, bout, v, uemb, pred);
}